// Round 10
// baseline (404.704 us; speedup 1.0000x reference)
//
#include <hip/hip_runtime.h>

// N=20000, E=640000, D_IN=256, HID1=512 (4 heads x 128), D_OUT=128, R=32.
// fp32 in/out; internal h1/h2/t2/x_mod bf16.
// Aggregates: batched global_load_lds ring with explicit s_waitcnt drain
// (vmcnt(0) before consume, lgkmcnt(0) before ring reuse) — wave-level,
// no barriers (waves have divergent trip counts).

#define D_IN   256
#define HID1   512
#define NHEADS 4
#define DOUT   128
#define NREL   32
#define NEG_SLOPE 0.2f
#define M_PAD  20096   // 157*128 == 314*64
#define DB1    8       // agg1 batch depth (rows of 1KB)
#define DB2    16      // agg2 batch depth (rows of 256B)

// s_waitcnt immediates (gfx9 encoding): [3:0]+[15:14]=vmcnt, [6:4]=expcnt, [11:8]=lgkmcnt
#define WAIT_VM0()   __builtin_amdgcn_s_waitcnt(0x0f70)  // vmcnt(0), ignore exp/lgkm
#define WAIT_LGKM0() __builtin_amdgcn_s_waitcnt(0xc07f)  // lgkmcnt(0), ignore vm/exp

static __device__ __forceinline__ unsigned short f2b(float f) {
  union { float f; unsigned int i; } v; v.f = f;
  unsigned int x = v.i;
  return (unsigned short)((x + 0x7fffu + ((x >> 16) & 1u)) >> 16);
}
static __device__ __forceinline__ float lrelu(float x) {
  return x > 0.f ? x : NEG_SLOPE * x;
}
static __device__ __forceinline__ void acc8(float* acc, float w, uint4 r) {
  unsigned int u;
  union { unsigned int i; float f; } cl, ch;
  u = r.x; cl.i = u << 16; ch.i = u & 0xffff0000u; acc[0] += w * cl.f; acc[1] += w * ch.f;
  u = r.y; cl.i = u << 16; ch.i = u & 0xffff0000u; acc[2] += w * cl.f; acc[3] += w * ch.f;
  u = r.z; cl.i = u << 16; ch.i = u & 0xffff0000u; acc[4] += w * cl.f; acc[5] += w * ch.f;
  u = r.w; cl.i = u << 16; ch.i = u & 0xffff0000u; acc[6] += w * cl.f; acc[7] += w * ch.f;
}

typedef __attribute__((ext_vector_type(8))) short bf16x8;
typedef __attribute__((ext_vector_type(4))) float f32x4;

// ---- prep: edge counting + weight cast/transpose --------------------------
__global__ void prep_kernel(const int* __restrict__ src, const int* __restrict__ dst,
                            const int* __restrict__ et, int* __restrict__ counts,
                            int* __restrict__ deg, int E, int eb,
                            const float* __restrict__ W1, const float* __restrict__ W2,
                            unsigned short* __restrict__ W1T, unsigned short* __restrict__ W2T) {
  int b = blockIdx.x;
  if (b < eb) {
    int e = b * 256 + threadIdx.x;
    if (e >= E) return;
    atomicAdd(&counts[(size_t)src[e] * NREL + et[e]], 1);
    atomicAdd(&deg[dst[e]], 1);
  } else {
    int idx = (b - eb) * 256 + threadIdx.x;
    if (idx < D_IN * HID1) {
      int r = idx / HID1, c = idx % HID1;
      W1T[(size_t)c * D_IN + r] = f2b(W1[idx]);
    } else {
      int k = idx - D_IN * HID1;
      if (k < HID1 * DOUT) {
        int r = k / DOUT, c = k % DOUT;
        W2T[(size_t)c * HID1 + r] = f2b(W2[k]);
      }
    }
  }
}

// ---- scan -----------------------------------------------------------------
__global__ void scan_local(const int* __restrict__ in, int* __restrict__ out,
                           int* __restrict__ bsum, int n) {
  __shared__ int wsum[4];
  int t = threadIdx.x;
  int base = blockIdx.x * 1024 + t * 4;
  int v0 = (base + 0 < n) ? in[base + 0] : 0;
  int v1 = (base + 1 < n) ? in[base + 1] : 0;
  int v2 = (base + 2 < n) ? in[base + 2] : 0;
  int v3 = (base + 3 < n) ? in[base + 3] : 0;
  int s = v0 + v1 + v2 + v3;
  int lane = t & 63, w = t >> 6;
  int sc = s;
  for (int off = 1; off < 64; off <<= 1) {
    int u = __shfl_up(sc, off);
    if (lane >= off) sc += u;
  }
  if (lane == 63) wsum[w] = sc;
  __syncthreads();
  int woff = 0;
  for (int i = 0; i < w; ++i) woff += wsum[i];
  int excl = woff + sc - s;
  if (base + 0 < n) out[base + 0] = excl;
  if (base + 1 < n) out[base + 1] = excl + v0;
  if (base + 2 < n) out[base + 2] = excl + v0 + v1;
  if (base + 3 < n) out[base + 3] = excl + v0 + v1 + v2;
  if (t == 255) bsum[blockIdx.x] = woff + sc;
}

// wave 0: bsum -> exclusive prefix. all: vs = W2*att_s2, vd = W2*att_d2.
__global__ void scan_blocks(int* __restrict__ bsum, int nb,
                            int* __restrict__ offsets, int n,
                            const float* __restrict__ W2,
                            const float* __restrict__ att_s2, const float* __restrict__ att_d2,
                            float* __restrict__ vs, float* __restrict__ vd) {
  int t = threadIdx.x;  // 256
  if (t < 64) {
    int v = (t < nb) ? bsum[t] : 0;
    int sc = v;
    for (int off = 1; off < 64; off <<= 1) {
      int u = __shfl_up(sc, off);
      if (t >= off) sc += u;
    }
    if (t < nb) bsum[t] = sc - v;
    if (t == nb - 1) offsets[n] = v;
  }
#pragma unroll
  for (int rr = 0; rr < 2; ++rr) {
    int r = t * 2 + rr;  // 0..511
    float ss = 0.f, dd = 0.f;
    for (int c = 0; c < DOUT; ++c) {
      float wv = W2[(size_t)r * DOUT + c];
      ss += wv * att_s2[c];
      dd += wv * att_d2[c];
    }
    vs[r] = ss; vd[r] = dd;
  }
}

__global__ void scatter_kernel(const int* __restrict__ src, const int* __restrict__ dst,
                               const int* __restrict__ offsets, const int* __restrict__ bsum,
                               int* __restrict__ cursor, int* __restrict__ csr_src,
                               int* __restrict__ csr_dst, int E) {
  int e = blockIdx.x * 256 + threadIdx.x;
  if (e >= E) return;
  int d = dst[e];
  int pos = offsets[d] + bsum[d >> 10] + atomicAdd(&cursor[d], 1);
  csr_src[pos] = src[e];
  csr_dst[pos] = d;
}

// ---- x_mod (float4 vectorized, 4 nodes/block) -----------------------------
__global__ __launch_bounds__(256) void xmod_kernel(
    const float* __restrict__ x, const int* __restrict__ counts,
    const float* __restrict__ rel, unsigned short* __restrict__ x_modb, int n_nodes) {
  int wv = threadIdx.x >> 6;
  int node = blockIdx.x * 4 + wv;
  if (node >= n_nodes) return;
  int l = threadIdx.x & 63;
  int cnt_l = counts[(size_t)node * NREL + (l & 31)];
  const float4* x4 = (const float4*)x;
  const float4* rel4 = (const float4*)rel;
  float4 v = x4[(size_t)node * 64 + l];
#pragma unroll
  for (int r = 0; r < NREL; ++r) {
    int c = __shfl(cnt_l, r);  // wave-uniform
    if (c) {
      float4 rv = rel4[r * 64 + l];
      float fc = (float)c;
      v.x += fc * rv.x; v.y += fc * rv.y; v.z += fc * rv.z; v.w += fc * rv.w;
    }
  }
  ushort4 o;
  o.x = f2b(v.x); o.y = f2b(v.y); o.z = f2b(v.z); o.w = f2b(v.w);
  *(ushort4*)(x_modb + (size_t)node * D_IN + l * 4) = o;
}

// ---- bf16 MFMA GEMM (+ optional fused alpha epilogue) ---------------------
template <int BM, bool ALPHA>
__global__ __launch_bounds__(256) void mfma_gemm(
    const unsigned short* __restrict__ A, const unsigned short* __restrict__ BT,
    unsigned short* __restrict__ C, int M, int N, int K,
    const float* __restrict__ att_s, const float* __restrict__ att_d,
    float* __restrict__ as_out, float* __restrict__ ad_out) {
  constexpr int MFR = BM / 32;
  __shared__ __align__(16) unsigned short Asl[BM * 32];
  __shared__ __align__(16) unsigned short Bsl[128 * 32];
  int tid = threadIdx.x;
  int m0 = blockIdx.y * BM, n0 = blockIdx.x * 128;
  int lane = tid & 63, wv = tid >> 6;
  int wm = wv & 1, wn = wv >> 1;
  int l16 = lane & 15, quad = lane >> 4;
  int lr = lane >> 2, lseg = lane & 3;

  f32x4 acc[MFR][4];
#pragma unroll
  for (int i = 0; i < MFR; ++i)
#pragma unroll
    for (int j = 0; j < 4; ++j) acc[i][j] = (f32x4)(0.f);

  for (int k0 = 0; k0 < K; k0 += 32) {
#pragma unroll
    for (int c = wv; c < BM / 16; c += 4) {
      int gr = m0 + c * 16 + lr; gr = gr < M ? gr : M - 1;
      __builtin_amdgcn_global_load_lds(
          (const __attribute__((address_space(1))) void*)(A + (size_t)gr * K + k0 + lseg * 8),
          (__attribute__((address_space(3))) void*)(&Asl[c * 512]), 16, 0, 0);
    }
#pragma unroll
    for (int c = wv; c < 8; c += 4) {
      int gr = n0 + c * 16 + lr;
      __builtin_amdgcn_global_load_lds(
          (const __attribute__((address_space(1))) void*)(BT + (size_t)gr * K + k0 + lseg * 8),
          (__attribute__((address_space(3))) void*)(&Bsl[c * 512]), 16, 0, 0);
    }
    __syncthreads();
    bf16x8 af[MFR], bfr[4];
#pragma unroll
    for (int mf = 0; mf < MFR; ++mf)
      af[mf] = *(const bf16x8*)(&Asl[(wm * (BM / 2) + mf * 16 + l16) * 32 + quad * 8]);
#pragma unroll
    for (int nf = 0; nf < 4; ++nf)
      bfr[nf] = *(const bf16x8*)(&Bsl[(wn * 64 + nf * 16 + l16) * 32 + quad * 8]);
#pragma unroll
    for (int mf = 0; mf < MFR; ++mf)
#pragma unroll
      for (int nf = 0; nf < 4; ++nf)
        acc[mf][nf] = __builtin_amdgcn_mfma_f32_16x16x32_bf16(af[mf], bfr[nf], acc[mf][nf], 0, 0, 0);
    __syncthreads();
  }
#pragma unroll
  for (int mf = 0; mf < MFR; ++mf)
#pragma unroll
    for (int nf = 0; nf < 4; ++nf)
#pragma unroll
      for (int r = 0; r < 4; ++r) {
        int row = m0 + wm * (BM / 2) + mf * 16 + quad * 4 + r;
        int col = n0 + wn * 64 + nf * 16 + l16;
        C[(size_t)row * N + col] = f2b(acc[mf][nf][r]);
      }
  if constexpr (ALPHA) {
    int head = blockIdx.x;
    float asw[4], adw[4];
#pragma unroll
    for (int nf = 0; nf < 4; ++nf) {
      int cl = wn * 64 + nf * 16 + l16;
      asw[nf] = att_s[head * 128 + cl];
      adw[nf] = att_d[head * 128 + cl];
    }
#pragma unroll
    for (int mf = 0; mf < MFR; ++mf)
#pragma unroll
      for (int r = 0; r < 4; ++r) {
        float sd = acc[mf][0][r] * asw[0] + acc[mf][1][r] * asw[1] +
                   acc[mf][2][r] * asw[2] + acc[mf][3][r] * asw[3];
        float dd = acc[mf][0][r] * adw[0] + acc[mf][1][r] * adw[1] +
                   acc[mf][2][r] * adw[2] + acc[mf][3][r] * adw[3];
#pragma unroll
        for (int off = 1; off < 16; off <<= 1) {
          sd += __shfl_xor(sd, off);
          dd += __shfl_xor(dd, off);
        }
        int row = m0 + wm * (BM / 2) + mf * 16 + quad * 4 + r;
        if (l16 == 0 && row < M) {
          atomicAdd(&as_out[row * NHEADS + head], sd);
          atomicAdd(&ad_out[row * NHEADS + head], dd);
        }
      }
  }
}

// ---- edge-parallel weight kernels -----------------------------------------
__global__ void weights1_kernel(const int* __restrict__ csr_src, const int* __restrict__ csr_dst,
                                const float* __restrict__ as1, const float* __restrict__ ad1,
                                float* __restrict__ wls, int E) {
  int e = blockIdx.x * 256 + threadIdx.x;
  if (e >= E) return;
  float4 a = ((const float4*)as1)[csr_src[e]];
  float4 b = ((const float4*)ad1)[csr_dst[e]];
  float4 w;
  w.x = __expf(lrelu(a.x + b.x));
  w.y = __expf(lrelu(a.y + b.y));
  w.z = __expf(lrelu(a.z + b.z));
  w.w = __expf(lrelu(a.w + b.w));
  ((float4*)wls)[e] = w;
}

__global__ void weights2_kernel(const int* __restrict__ csr_src, const int* __restrict__ csr_dst,
                                const float* __restrict__ as2, const float* __restrict__ ad2,
                                float* __restrict__ w2, int E) {
  int e = blockIdx.x * 256 + threadIdx.x;
  if (e >= E) return;
  w2[e] = __expf(lrelu(as2[csr_src[e]] + ad2[csr_dst[e]]));
}

// ---- layer-1 aggregate: batched LDS-ring gather, one wave/node ------------
// lane owns ch [8*lane..8*lane+7]; head = lane>>4; denom complete per lane.
__global__ __launch_bounds__(256) void aggregate1_kernel(
    const unsigned short* __restrict__ h1b,
    const float* __restrict__ as1, const float* __restrict__ ad1,
    const int* __restrict__ offsets, const int* __restrict__ bsum,
    const int* __restrict__ csr_src, const float* __restrict__ wls,
    const float* __restrict__ bias, const float* __restrict__ vs,
    const float* __restrict__ vd, unsigned short* __restrict__ h2b,
    float* __restrict__ as2, float* __restrict__ ad2, int n_nodes) {
  __shared__ __align__(16) unsigned short ring[4][DB1 * 512];
  int wv = threadIdx.x >> 6;
  int node = blockIdx.x * 4 + wv;
  if (node >= n_nodes) return;
  int lane = threadIdx.x & 63;
  int head = lane >> 4;
  int lo = offsets[node] + bsum[node >> 10];
  int hi = offsets[node + 1] + bsum[(node + 1) >> 10];
  unsigned short* myring = ring[wv];
  float acc[8] = {0.f, 0.f, 0.f, 0.f, 0.f, 0.f, 0.f, 0.f};
  float denom = 0.f;

  for (int j = lo; j < hi; j += DB1) {
    int nb = hi - j; nb = nb < DB1 ? nb : DB1;
    int sidx = j + (lane & 7); sidx = sidx < hi ? sidx : hi - 1;
    int sv = csr_src[sidx];
    float wl = wls[(size_t)sidx * 4 + head];
    for (int k = 0; k < nb; ++k) {
      int s = __shfl(sv, k);
      __builtin_amdgcn_global_load_lds(
          (const __attribute__((address_space(1))) void*)(h1b + (size_t)s * HID1 + lane * 8),
          (__attribute__((address_space(3))) void*)(&myring[k * 512]), 16, 0, 0);
    }
    WAIT_VM0();  // drain DMA into LDS before reading the ring
    for (int k = 0; k < nb; ++k) {
      float w = __shfl(wl, (head << 4) | k);
      uint4 r = *(const uint4*)(&myring[k * 512 + lane * 8]);
      acc8(acc, w, r);
      denom += w;
    }
    WAIT_LGKM0();  // ds_reads returned before ring is overwritten (WAR)
  }
  // self loop
  float4 asn = ((const float4*)as1)[node];
  float4 ad4 = ((const float4*)ad1)[node];
  float as_own = head == 0 ? asn.x : head == 1 ? asn.y : head == 2 ? asn.z : asn.w;
  float ad_own = head == 0 ? ad4.x : head == 1 ? ad4.y : head == 2 ? ad4.z : ad4.w;
  float wself = __expf(lrelu(as_own + ad_own));
  uint4 own = *(const uint4*)(h1b + (size_t)node * HID1 + lane * 8);
  acc8(acc, wself, own);
  denom += wself;

  float inv = 1.f / (denom + 1e-16f);
  float ss = 0.f, dd = 0.f;
  unsigned int od[4];
#pragma unroll
  for (int q = 0; q < 4; ++q) {
    int ch = lane * 8 + 2 * q;
    float vlo = acc[2 * q] * inv + bias[ch];
    float vhi = acc[2 * q + 1] * inv + bias[ch + 1];
    vlo = vlo > 0.f ? vlo : expm1f(vlo);
    vhi = vhi > 0.f ? vhi : expm1f(vhi);
    ss += vlo * vs[ch] + vhi * vs[ch + 1];
    dd += vlo * vd[ch] + vhi * vd[ch + 1];
    od[q] = (unsigned int)f2b(vlo) | ((unsigned int)f2b(vhi) << 16);
  }
  uint4 o; o.x = od[0]; o.y = od[1]; o.z = od[2]; o.w = od[3];
  *(uint4*)(h2b + (size_t)node * HID1 + lane * 8) = o;
  for (int off = 32; off; off >>= 1) {
    ss += __shfl_xor(ss, off);
    dd += __shfl_xor(dd, off);
  }
  if (lane == 0) { as2[node] = ss; ad2[node] = dd; }
}

// ---- layer-2 aggregate: batched LDS-ring gather, one wave/node ------------
__global__ __launch_bounds__(256) void aggregate2_kernel(
    const unsigned short* __restrict__ t2b,
    const float* __restrict__ as2, const float* __restrict__ ad2,
    const int* __restrict__ offsets, const int* __restrict__ bsum,
    const int* __restrict__ csr_src, const float* __restrict__ w2,
    const float* __restrict__ bias, float* __restrict__ out, int n_nodes) {
  __shared__ __align__(16) unsigned short ring[4][DB2 * 128];
  int wv = threadIdx.x >> 6;
  int node = blockIdx.x * 4 + wv;
  if (node >= n_nodes) return;
  int lane = threadIdx.x & 63;
  int lo = offsets[node] + bsum[node >> 10];
  int hi = offsets[node + 1] + bsum[(node + 1) >> 10];
  unsigned short* myring = ring[wv];
  float a0 = 0.f, a1 = 0.f, denom = 0.f;

  for (int j = lo; j < hi; j += DB2) {
    int nb = hi - j; nb = nb < DB2 ? nb : DB2;
    int sidx = j + (lane & 15); sidx = sidx < hi ? sidx : hi - 1;
    int sv = csr_src[sidx];
    float wl = w2[sidx];
    for (int k = 0; k < nb; ++k) {
      int s = __shfl(sv, k);
      __builtin_amdgcn_global_load_lds(
          (const __attribute__((address_space(1))) void*)(t2b + (size_t)s * DOUT + lane * 2),
          (__attribute__((address_space(3))) void*)(&myring[k * 128]), 4, 0, 0);
    }
    WAIT_VM0();
    for (int k = 0; k < nb; ++k) {
      float w = __shfl(wl, k);
      unsigned int u = *(const unsigned int*)(&myring[k * 128 + lane * 2]);
      union { unsigned int i; float f; } cl, ch;
      cl.i = u << 16; ch.i = u & 0xffff0000u;
      a0 += w * cl.f; a1 += w * ch.f;
      denom += w;
    }
    WAIT_LGKM0();
  }
  // self loop
  float wself = __expf(lrelu(as2[node] + ad2[node]));
  {
    unsigned int u = *(const unsigned int*)(t2b + (size_t)node * DOUT + lane * 2);
    union { unsigned int i; float f; } cl, ch;
    cl.i = u << 16; ch.i = u & 0xffff0000u;
    a0 += wself * cl.f; a1 += wself * ch.f;
    denom += wself;
  }
  float inv = 1.f / (denom + 1e-16f);
  float2 o;
  o.x = a0 * inv + bias[lane * 2];
  o.y = a1 * inv + bias[lane * 2 + 1];
  *(float2*)(out + (size_t)node * DOUT + lane * 2) = o;
}

extern "C" void kernel_launch(void* const* d_in, const int* in_sizes, int n_in,
                              void* d_out, int out_size, void* d_ws, size_t ws_size,
                              hipStream_t stream) {
  const float* x     = (const float*)d_in[0];
  const int* ei      = (const int*)d_in[1];
  const int* etype   = (const int*)d_in[2];
  const float* rel   = (const float*)d_in[3];
  const float* W1    = (const float*)d_in[4];
  const float* at_s1 = (const float*)d_in[5];
  const float* at_d1 = (const float*)d_in[6];
  const float* b1    = (const float*)d_in[7];
  const float* W2    = (const float*)d_in[8];
  const float* at_s2 = (const float*)d_in[9];
  const float* at_d2 = (const float*)d_in[10];
  const float* b2v   = (const float*)d_in[11];
  float* out         = (float*)d_out;

  const int N = in_sizes[0] / D_IN;  // 20000
  const int E = in_sizes[2];         // 640000
  const int* srcv = ei;
  const int* dstv = ei + E;

  char* p = (char*)d_ws;
  auto carve = [&](size_t bytes) -> char* {
    char* r = p; p += (bytes + 255) & ~(size_t)255; return r;
  };
  // zeroed region
  int*   counts  = (int*)carve((size_t)N * NREL * 4);
  int*   deg     = (int*)carve((size_t)N * 4);
  int*   offsets = (int*)carve(((size_t)N + 1) * 4);
  int*   cursor  = (int*)carve((size_t)N * 4);
  int*   bsum    = (int*)carve(64 * 4);
  float* as1     = (float*)carve((size_t)N * NHEADS * 4);
  float* ad1     = (float*)carve((size_t)N * NHEADS * 4);
  size_t zero_bytes = (size_t)(p - (char*)counts);
  // plain scratch
  float* as2     = (float*)carve((size_t)N * 4);
  float* ad2     = (float*)carve((size_t)N * 4);
  float* vs      = (float*)carve((size_t)HID1 * 4);
  float* vd      = (float*)carve((size_t)HID1 * 4);
  int*   csr_src = (int*)carve((size_t)E * 4);
  int*   csr_dst = (int*)carve((size_t)E * 4);
  float* wls     = (float*)carve((size_t)E * NHEADS * 4);
  float* w2      = (float*)carve((size_t)E * 4);
  unsigned short* W1T    = (unsigned short*)carve((size_t)HID1 * D_IN * 2);
  unsigned short* W2T    = (unsigned short*)carve((size_t)DOUT * HID1 * 2);
  unsigned short* x_modb = (unsigned short*)carve((size_t)M_PAD * D_IN * 2);
  unsigned short* h1b    = (unsigned short*)carve((size_t)M_PAD * HID1 * 2);
  unsigned short* h2b    = (unsigned short*)carve((size_t)M_PAD * HID1 * 2);
  unsigned short* t2b    = (unsigned short*)carve((size_t)M_PAD * DOUT * 2);

  hipMemsetAsync(counts, 0, zero_bytes, stream);

  int eb = (E + 255) / 256;                          // 2500
  int cb = (D_IN * HID1 + HID1 * DOUT + 255) / 256;  // 768
  int nb = (N + 1023) / 1024;                        // 20
  prep_kernel<<<eb + cb, 256, 0, stream>>>(srcv, dstv, etype, counts, deg, E, eb,
                                           W1, W2, W1T, W2T);
  scan_local<<<nb, 256, 0, stream>>>(deg, offsets, bsum, N);
  scan_blocks<<<1, 256, 0, stream>>>(bsum, nb, offsets, N, W2, at_s2, at_d2, vs, vd);
  scatter_kernel<<<eb, 256, 0, stream>>>(srcv, dstv, offsets, bsum, cursor,
                                         csr_src, csr_dst, E);
  xmod_kernel<<<(N + 3) / 4, 256, 0, stream>>>(x, counts, rel, x_modb, N);
  mfma_gemm<128, true><<<dim3(HID1 / 128, M_PAD / 128), 256, 0, stream>>>(
      x_modb, W1T, h1b, N, HID1, D_IN, at_s1, at_d1, as1, ad1);
  weights1_kernel<<<eb, 256, 0, stream>>>(csr_src, csr_dst, as1, ad1, wls, E);
  aggregate1_kernel<<<(N + 3) / 4, 256, 0, stream>>>(
      h1b, as1, ad1, offsets, bsum, csr_src, wls, b1, vs, vd, h2b, as2, ad2, N);
  weights2_kernel<<<eb, 256, 0, stream>>>(csr_src, csr_dst, as2, ad2, w2, E);
  mfma_gemm<64, false><<<dim3(DOUT / 128, M_PAD / 64), 256, 0, stream>>>(
      h2b, W2T, t2b, N, DOUT, HID1, nullptr, nullptr, nullptr, nullptr);
  aggregate2_kernel<<<(N + 3) / 4, 256, 0, stream>>>(
      t2b, as2, ad2, offsets, bsum, csr_src, w2, b2v, out, N);
}

// Round 11
// 384.456 us; speedup vs baseline: 1.0527x; 1.0527x over previous
//
#include <hip/hip_runtime.h>

// N=20000, E=640000, D_IN=256, HID1=512 (4 heads x 128), D_OUT=128, R=32.
// fp32 in/out; internal h1/h2/t2/x_mod bf16.
// Round-8 champion aggregate structure (register-pipelined, 1-ahead) +
// streaming per-edge weights (computed in scatter, fused) + fused as2/ad2
// epilogue in aggregate1. 9 kernels.

#define D_IN   256
#define HID1   512
#define NHEADS 4
#define DOUT   128
#define NREL   32
#define NEG_SLOPE 0.2f
#define M_PAD  20096   // 157*128 == 314*64

static __device__ __forceinline__ unsigned short f2b(float f) {
  union { float f; unsigned int i; } v; v.f = f;
  unsigned int x = v.i;
  return (unsigned short)((x + 0x7fffu + ((x >> 16) & 1u)) >> 16);
}
static __device__ __forceinline__ float lrelu(float x) {
  return x > 0.f ? x : NEG_SLOPE * x;
}
static __device__ __forceinline__ void acc8(float* acc, float w, uint4 r) {
  unsigned int u;
  union { unsigned int i; float f; } cl, ch;
  u = r.x; cl.i = u << 16; ch.i = u & 0xffff0000u; acc[0] += w * cl.f; acc[1] += w * ch.f;
  u = r.y; cl.i = u << 16; ch.i = u & 0xffff0000u; acc[2] += w * cl.f; acc[3] += w * ch.f;
  u = r.z; cl.i = u << 16; ch.i = u & 0xffff0000u; acc[4] += w * cl.f; acc[5] += w * ch.f;
  u = r.w; cl.i = u << 16; ch.i = u & 0xffff0000u; acc[6] += w * cl.f; acc[7] += w * ch.f;
}

typedef __attribute__((ext_vector_type(8))) short bf16x8;
typedef __attribute__((ext_vector_type(4))) float f32x4;

// ---- prep: edge counting + weight cast/transpose --------------------------
__global__ void prep_kernel(const int* __restrict__ src, const int* __restrict__ dst,
                            const int* __restrict__ et, int* __restrict__ counts,
                            int* __restrict__ deg, int E, int eb,
                            const float* __restrict__ W1, const float* __restrict__ W2,
                            unsigned short* __restrict__ W1T, unsigned short* __restrict__ W2T) {
  int b = blockIdx.x;
  if (b < eb) {
    int e = b * 256 + threadIdx.x;
    if (e >= E) return;
    atomicAdd(&counts[(size_t)src[e] * NREL + et[e]], 1);
    atomicAdd(&deg[dst[e]], 1);
  } else {
    int idx = (b - eb) * 256 + threadIdx.x;
    if (idx < D_IN * HID1) {
      int r = idx / HID1, c = idx % HID1;
      W1T[(size_t)c * D_IN + r] = f2b(W1[idx]);
    } else {
      int k = idx - D_IN * HID1;
      if (k < HID1 * DOUT) {
        int r = k / DOUT, c = k % DOUT;
        W2T[(size_t)c * HID1 + r] = f2b(W2[k]);
      }
    }
  }
}

// ---- scan -----------------------------------------------------------------
__global__ void scan_local(const int* __restrict__ in, int* __restrict__ out,
                           int* __restrict__ bsum, int n) {
  __shared__ int wsum[4];
  int t = threadIdx.x;
  int base = blockIdx.x * 1024 + t * 4;
  int v0 = (base + 0 < n) ? in[base + 0] : 0;
  int v1 = (base + 1 < n) ? in[base + 1] : 0;
  int v2 = (base + 2 < n) ? in[base + 2] : 0;
  int v3 = (base + 3 < n) ? in[base + 3] : 0;
  int s = v0 + v1 + v2 + v3;
  int lane = t & 63, w = t >> 6;
  int sc = s;
  for (int off = 1; off < 64; off <<= 1) {
    int u = __shfl_up(sc, off);
    if (lane >= off) sc += u;
  }
  if (lane == 63) wsum[w] = sc;
  __syncthreads();
  int woff = 0;
  for (int i = 0; i < w; ++i) woff += wsum[i];
  int excl = woff + sc - s;
  if (base + 0 < n) out[base + 0] = excl;
  if (base + 1 < n) out[base + 1] = excl + v0;
  if (base + 2 < n) out[base + 2] = excl + v0 + v1;
  if (base + 3 < n) out[base + 3] = excl + v0 + v1 + v2;
  if (t == 255) bsum[blockIdx.x] = woff + sc;
}

// wave 0: bsum -> exclusive prefix. all threads: vs = W2*att_s2, vd = W2*att_d2.
__global__ void scan_blocks(int* __restrict__ bsum, int nb,
                            int* __restrict__ offsets, int n,
                            const float* __restrict__ W2,
                            const float* __restrict__ att_s2, const float* __restrict__ att_d2,
                            float* __restrict__ vs, float* __restrict__ vd) {
  int t = threadIdx.x;  // 256
  if (t < 64) {
    int v = (t < nb) ? bsum[t] : 0;
    int sc = v;
    for (int off = 1; off < 64; off <<= 1) {
      int u = __shfl_up(sc, off);
      if (t >= off) sc += u;
    }
    if (t < nb) bsum[t] = sc - v;
    if (t == nb - 1) offsets[n] = v;
  }
#pragma unroll
  for (int rr = 0; rr < 2; ++rr) {
    int r = t * 2 + rr;  // 0..511
    float ss = 0.f, dd = 0.f;
    for (int c = 0; c < DOUT; ++c) {
      float wv = W2[(size_t)r * DOUT + c];
      ss += wv * att_s2[c];
      dd += wv * att_d2[c];
    }
    vs[r] = ss; vd[r] = dd;
  }
}

// ---- scatter + fused layer-1 edge weights (runs AFTER gemm1) --------------
__global__ void scatter_w_kernel(const int* __restrict__ src, const int* __restrict__ dst,
                                 const int* __restrict__ offsets, const int* __restrict__ bsum,
                                 int* __restrict__ cursor, int* __restrict__ csr_src,
                                 const float* __restrict__ as1, const float* __restrict__ ad1,
                                 float* __restrict__ wls, int E) {
  int e = blockIdx.x * 256 + threadIdx.x;
  if (e >= E) return;
  int d = dst[e];
  int s = src[e];
  int pos = offsets[d] + bsum[d >> 10] + atomicAdd(&cursor[d], 1);
  csr_src[pos] = s;
  float4 a = ((const float4*)as1)[s];
  float4 b = ((const float4*)ad1)[d];
  float4 w;
  w.x = __expf(lrelu(a.x + b.x));
  w.y = __expf(lrelu(a.y + b.y));
  w.z = __expf(lrelu(a.z + b.z));
  w.w = __expf(lrelu(a.w + b.w));
  ((float4*)wls)[pos] = w;
}

// ---- x_mod (float4 vectorized, 4 nodes/block) -----------------------------
__global__ __launch_bounds__(256) void xmod_kernel(
    const float* __restrict__ x, const int* __restrict__ counts,
    const float* __restrict__ rel, unsigned short* __restrict__ x_modb, int n_nodes) {
  int wv = threadIdx.x >> 6;
  int node = blockIdx.x * 4 + wv;
  if (node >= n_nodes) return;
  int l = threadIdx.x & 63;
  int cnt_l = counts[(size_t)node * NREL + (l & 31)];
  const float4* x4 = (const float4*)x;
  const float4* rel4 = (const float4*)rel;
  float4 v = x4[(size_t)node * 64 + l];
#pragma unroll
  for (int r = 0; r < NREL; ++r) {
    int c = __shfl(cnt_l, r);  // wave-uniform
    if (c) {
      float4 rv = rel4[r * 64 + l];
      float fc = (float)c;
      v.x += fc * rv.x; v.y += fc * rv.y; v.z += fc * rv.z; v.w += fc * rv.w;
    }
  }
  ushort4 o;
  o.x = f2b(v.x); o.y = f2b(v.y); o.z = f2b(v.z); o.w = f2b(v.w);
  *(ushort4*)(x_modb + (size_t)node * D_IN + l * 4) = o;
}

// ---- bf16 MFMA GEMM (+ optional fused alpha epilogue) ---------------------
template <int BM, bool ALPHA>
__global__ __launch_bounds__(256) void mfma_gemm(
    const unsigned short* __restrict__ A, const unsigned short* __restrict__ BT,
    unsigned short* __restrict__ C, int M, int N, int K,
    const float* __restrict__ att_s, const float* __restrict__ att_d,
    float* __restrict__ as_out, float* __restrict__ ad_out) {
  constexpr int MFR = BM / 32;
  __shared__ __align__(16) unsigned short Asl[BM * 32];
  __shared__ __align__(16) unsigned short Bsl[128 * 32];
  int tid = threadIdx.x;
  int m0 = blockIdx.y * BM, n0 = blockIdx.x * 128;
  int lane = tid & 63, wv = tid >> 6;
  int wm = wv & 1, wn = wv >> 1;
  int l16 = lane & 15, quad = lane >> 4;
  int lr = lane >> 2, lseg = lane & 3;

  f32x4 acc[MFR][4];
#pragma unroll
  for (int i = 0; i < MFR; ++i)
#pragma unroll
    for (int j = 0; j < 4; ++j) acc[i][j] = (f32x4)(0.f);

  for (int k0 = 0; k0 < K; k0 += 32) {
#pragma unroll
    for (int c = wv; c < BM / 16; c += 4) {
      int gr = m0 + c * 16 + lr; gr = gr < M ? gr : M - 1;
      __builtin_amdgcn_global_load_lds(
          (const __attribute__((address_space(1))) void*)(A + (size_t)gr * K + k0 + lseg * 8),
          (__attribute__((address_space(3))) void*)(&Asl[c * 512]), 16, 0, 0);
    }
#pragma unroll
    for (int c = wv; c < 8; c += 4) {
      int gr = n0 + c * 16 + lr;
      __builtin_amdgcn_global_load_lds(
          (const __attribute__((address_space(1))) void*)(BT + (size_t)gr * K + k0 + lseg * 8),
          (__attribute__((address_space(3))) void*)(&Bsl[c * 512]), 16, 0, 0);
    }
    __syncthreads();
    bf16x8 af[MFR], bfr[4];
#pragma unroll
    for (int mf = 0; mf < MFR; ++mf)
      af[mf] = *(const bf16x8*)(&Asl[(wm * (BM / 2) + mf * 16 + l16) * 32 + quad * 8]);
#pragma unroll
    for (int nf = 0; nf < 4; ++nf)
      bfr[nf] = *(const bf16x8*)(&Bsl[(wn * 64 + nf * 16 + l16) * 32 + quad * 8]);
#pragma unroll
    for (int mf = 0; mf < MFR; ++mf)
#pragma unroll
      for (int nf = 0; nf < 4; ++nf)
        acc[mf][nf] = __builtin_amdgcn_mfma_f32_16x16x32_bf16(af[mf], bfr[nf], acc[mf][nf], 0, 0, 0);
    __syncthreads();
  }
#pragma unroll
  for (int mf = 0; mf < MFR; ++mf)
#pragma unroll
    for (int nf = 0; nf < 4; ++nf)
#pragma unroll
      for (int r = 0; r < 4; ++r) {
        int row = m0 + wm * (BM / 2) + mf * 16 + quad * 4 + r;
        int col = n0 + wn * 64 + nf * 16 + l16;
        C[(size_t)row * N + col] = f2b(acc[mf][nf][r]);
      }
  if constexpr (ALPHA) {
    int head = blockIdx.x;
    float asw[4], adw[4];
#pragma unroll
    for (int nf = 0; nf < 4; ++nf) {
      int cl = wn * 64 + nf * 16 + l16;
      asw[nf] = att_s[head * 128 + cl];
      adw[nf] = att_d[head * 128 + cl];
    }
#pragma unroll
    for (int mf = 0; mf < MFR; ++mf)
#pragma unroll
      for (int r = 0; r < 4; ++r) {
        float sd = acc[mf][0][r] * asw[0] + acc[mf][1][r] * asw[1] +
                   acc[mf][2][r] * asw[2] + acc[mf][3][r] * asw[3];
        float dd = acc[mf][0][r] * adw[0] + acc[mf][1][r] * adw[1] +
                   acc[mf][2][r] * adw[2] + acc[mf][3][r] * adw[3];
#pragma unroll
        for (int off = 1; off < 16; off <<= 1) {
          sd += __shfl_xor(sd, off);
          dd += __shfl_xor(dd, off);
        }
        int row = m0 + wm * (BM / 2) + mf * 16 + quad * 4 + r;
        if (l16 == 0 && row < M) {
          atomicAdd(&as_out[row * NHEADS + head], sd);
          atomicAdd(&ad_out[row * NHEADS + head], dd);
        }
      }
  }
}

// ---- layer-1 aggregate: one wave/node, 2 groups, streaming wls ------------
// group g=lane>>5 handles edge lo+2i+g; lane covers ch [16*l32..16*l32+15]
__global__ __launch_bounds__(256) void aggregate1_kernel(
    const unsigned short* __restrict__ h1b,
    const float* __restrict__ as1, const float* __restrict__ ad1,
    const int* __restrict__ offsets, const int* __restrict__ bsum,
    const int* __restrict__ csr_src, const float* __restrict__ wls,
    const float* __restrict__ bias, const float* __restrict__ vs,
    const float* __restrict__ vd, unsigned short* __restrict__ h2b,
    float* __restrict__ as2, float* __restrict__ ad2, int n_nodes) {
  int node = blockIdx.x * 4 + (threadIdx.x >> 6);
  if (node >= n_nodes) return;
  int lane = threadIdx.x & 63;
  int g = lane >> 5, l32 = lane & 31;
  int head = l32 >> 3;
  int lo = offsets[node] + bsum[node >> 10];
  int hi = offsets[node + 1] + bsum[(node + 1) >> 10];

  const uint4* h1v = (const uint4*)h1b;
  float acc[16];
#pragma unroll
  for (int k = 0; k < 16; ++k) acc[k] = 0.f;
  float denom = 0.f;

  int nit = (hi - lo + 1) >> 1;
  int j = lo + g;
  bool valid = j < hi;
  int s = valid ? csr_src[j] : node;
  float wc = valid ? wls[(size_t)j * 4 + head] : 0.f;  // pipelined 1 ahead
  for (int i = 0; i < nit; ++i) {
    int jn = j + 2;
    bool vn = jn < hi;
    int sn = vn ? csr_src[jn] : node;
    float wn = vn ? wls[(size_t)jn * 4 + head] : 0.f;
    uint4 h0 = h1v[(size_t)s * 64 + l32 * 2];
    uint4 h1r = h1v[(size_t)s * 64 + l32 * 2 + 1];
    acc8(acc, wc, h0); acc8(acc + 8, wc, h1r);
    denom += wc;
    j = jn; valid = vn; s = sn; wc = wn;
  }
  // self loop (group 0 only, before cross-group reduce)
  float4 asn = ((const float4*)as1)[node];
  float4 ad4 = ((const float4*)ad1)[node];
  float as_own = head == 0 ? asn.x : head == 1 ? asn.y : head == 2 ? asn.z : asn.w;
  float ad_own = head == 0 ? ad4.x : head == 1 ? ad4.y : head == 2 ? ad4.z : ad4.w;
  if (g == 0) {
    float wself = __expf(lrelu(as_own + ad_own));
    uint4 h0 = h1v[(size_t)node * 64 + l32 * 2];
    uint4 h1r = h1v[(size_t)node * 64 + l32 * 2 + 1];
    acc8(acc, wself, h0); acc8(acc + 8, wself, h1r);
    denom += wself;
  }
#pragma unroll
  for (int k = 0; k < 16; ++k) acc[k] += __shfl_xor(acc[k], 32);
  denom += __shfl_xor(denom, 32);
  if (g == 0) {
    float inv = 1.f / (denom + 1e-16f);
    float ss = 0.f, dd = 0.f;
    unsigned int od[8];
#pragma unroll
    for (int q = 0; q < 8; ++q) {
      int ch = l32 * 16 + 2 * q;
      float vlo = acc[2 * q] * inv + bias[ch];
      float vhi = acc[2 * q + 1] * inv + bias[ch + 1];
      vlo = vlo > 0.f ? vlo : expm1f(vlo);  // ELU
      vhi = vhi > 0.f ? vhi : expm1f(vhi);
      ss += vlo * vs[ch] + vhi * vs[ch + 1];
      dd += vlo * vd[ch] + vhi * vd[ch + 1];
      od[q] = (unsigned int)f2b(vlo) | ((unsigned int)f2b(vhi) << 16);
    }
    uint4 o0; o0.x = od[0]; o0.y = od[1]; o0.z = od[2]; o0.w = od[3];
    uint4 o1; o1.x = od[4]; o1.y = od[5]; o1.z = od[6]; o1.w = od[7];
    ((uint4*)h2b)[(size_t)node * 64 + l32 * 2] = o0;
    ((uint4*)h2b)[(size_t)node * 64 + l32 * 2 + 1] = o1;
    // reduce ss/dd over the 32 lanes of group 0
#pragma unroll
    for (int off = 16; off; off >>= 1) {
      ss += __shfl_xor(ss, off);
      dd += __shfl_xor(dd, off);
    }
    if (l32 == 0) { as2[node] = ss; ad2[node] = dd; }
  }
}

// ---- layer-2 aggregate: one wave/node, 4 groups, pipelined as2 gather -----
// group g=lane>>4 handles edge lo+4i+g; lane covers ch [8*l16..8*l16+7]
__global__ __launch_bounds__(256) void aggregate2_kernel(
    const unsigned short* __restrict__ t2b,
    const float* __restrict__ as2, const float* __restrict__ ad2,
    const int* __restrict__ offsets, const int* __restrict__ bsum,
    const int* __restrict__ csr_src,
    const float* __restrict__ bias, float* __restrict__ out, int n_nodes) {
  int node = blockIdx.x * 4 + (threadIdx.x >> 6);
  if (node >= n_nodes) return;
  int lane = threadIdx.x & 63;
  int g = lane >> 4, l16 = lane & 15;
  int lo = offsets[node] + bsum[node >> 10];
  int hi = offsets[node + 1] + bsum[(node + 1) >> 10];
  float ad = ad2[node];

  const uint4* t2v = (const uint4*)t2b;
  float acc[8] = {0.f, 0.f, 0.f, 0.f, 0.f, 0.f, 0.f, 0.f};
  float denom = 0.f;
  int nit = (hi - lo + 3) >> 2;
  int j = lo + g;
  bool valid = j < hi;
  int s = valid ? csr_src[j] : node;
  float asv = as2[s];
  for (int i = 0; i < nit; ++i) {
    int jn = j + 4;
    bool vn = jn < hi;
    int sn = vn ? csr_src[jn] : node;
    float asv_n = as2[sn];
    uint4 tv = t2v[(size_t)s * 16 + l16];
    float w = valid ? __expf(lrelu(asv + ad)) : 0.f;
    acc8(acc, w, tv);
    denom += w;
    j = jn; valid = vn; s = sn; asv = asv_n;
  }
  if (g == 0) {  // self loop
    uint4 tv = t2v[(size_t)node * 16 + l16];
    float w = __expf(lrelu(as2[node] + ad));
    acc8(acc, w, tv);
    denom += w;
  }
#pragma unroll
  for (int k = 0; k < 8; ++k) {
    acc[k] += __shfl_xor(acc[k], 16);
    acc[k] += __shfl_xor(acc[k], 32);
  }
  denom += __shfl_xor(denom, 16);
  denom += __shfl_xor(denom, 32);
  if (g == 0) {
    float inv = 1.f / (denom + 1e-16f);
    float4 o0, o1;
    o0.x = acc[0] * inv + bias[l16 * 8 + 0];
    o0.y = acc[1] * inv + bias[l16 * 8 + 1];
    o0.z = acc[2] * inv + bias[l16 * 8 + 2];
    o0.w = acc[3] * inv + bias[l16 * 8 + 3];
    o1.x = acc[4] * inv + bias[l16 * 8 + 4];
    o1.y = acc[5] * inv + bias[l16 * 8 + 5];
    o1.z = acc[6] * inv + bias[l16 * 8 + 6];
    o1.w = acc[7] * inv + bias[l16 * 8 + 7];
    *(float4*)(out + (size_t)node * DOUT + l16 * 8) = o0;
    *(float4*)(out + (size_t)node * DOUT + l16 * 8 + 4) = o1;
  }
}

extern "C" void kernel_launch(void* const* d_in, const int* in_sizes, int n_in,
                              void* d_out, int out_size, void* d_ws, size_t ws_size,
                              hipStream_t stream) {
  const float* x     = (const float*)d_in[0];
  const int* ei      = (const int*)d_in[1];
  const int* etype   = (const int*)d_in[2];
  const float* rel   = (const float*)d_in[3];
  const float* W1    = (const float*)d_in[4];
  const float* at_s1 = (const float*)d_in[5];
  const float* at_d1 = (const float*)d_in[6];
  const float* b1    = (const float*)d_in[7];
  const float* W2    = (const float*)d_in[8];
  const float* at_s2 = (const float*)d_in[9];
  const float* at_d2 = (const float*)d_in[10];
  const float* b2v   = (const float*)d_in[11];
  float* out         = (float*)d_out;

  const int N = in_sizes[0] / D_IN;  // 20000
  const int E = in_sizes[2];         // 640000
  const int* srcv = ei;
  const int* dstv = ei + E;

  char* p = (char*)d_ws;
  auto carve = [&](size_t bytes) -> char* {
    char* r = p; p += (bytes + 255) & ~(size_t)255; return r;
  };
  // zeroed region
  int*   counts  = (int*)carve((size_t)N * NREL * 4);
  int*   deg     = (int*)carve((size_t)N * 4);
  int*   offsets = (int*)carve(((size_t)N + 1) * 4);
  int*   cursor  = (int*)carve((size_t)N * 4);
  int*   bsum    = (int*)carve(64 * 4);
  float* as1     = (float*)carve((size_t)N * NHEADS * 4);
  float* ad1     = (float*)carve((size_t)N * NHEADS * 4);
  size_t zero_bytes = (size_t)(p - (char*)counts);
  // plain scratch
  float* as2     = (float*)carve((size_t)N * 4);
  float* ad2     = (float*)carve((size_t)N * 4);
  float* vs      = (float*)carve((size_t)HID1 * 4);
  float* vd      = (float*)carve((size_t)HID1 * 4);
  int*   csr_src = (int*)carve((size_t)E * 4);
  float* wls     = (float*)carve((size_t)E * NHEADS * 4);
  unsigned short* W1T    = (unsigned short*)carve((size_t)HID1 * D_IN * 2);
  unsigned short* W2T    = (unsigned short*)carve((size_t)DOUT * HID1 * 2);
  unsigned short* x_modb = (unsigned short*)carve((size_t)M_PAD * D_IN * 2);
  unsigned short* h1b    = (unsigned short*)carve((size_t)M_PAD * HID1 * 2);
  unsigned short* h2b    = (unsigned short*)carve((size_t)M_PAD * HID1 * 2);
  unsigned short* t2b    = (unsigned short*)carve((size_t)M_PAD * DOUT * 2);

  hipMemsetAsync(counts, 0, zero_bytes, stream);

  int eb = (E + 255) / 256;                          // 2500
  int cb = (D_IN * HID1 + HID1 * DOUT + 255) / 256;  // 768
  int nb = (N + 1023) / 1024;                        // 20
  prep_kernel<<<eb + cb, 256, 0, stream>>>(srcv, dstv, etype, counts, deg, E, eb,
                                           W1, W2, W1T, W2T);
  scan_local<<<nb, 256, 0, stream>>>(deg, offsets, bsum, N);
  scan_blocks<<<1, 256, 0, stream>>>(bsum, nb, offsets, N, W2, at_s2, at_d2, vs, vd);
  xmod_kernel<<<(N + 3) / 4, 256, 0, stream>>>(x, counts, rel, x_modb, N);
  mfma_gemm<128, true><<<dim3(HID1 / 128, M_PAD / 128), 256, 0, stream>>>(
      x_modb, W1T, h1b, N, HID1, D_IN, at_s1, at_d1, as1, ad1);
  scatter_w_kernel<<<eb, 256, 0, stream>>>(srcv, dstv, offsets, bsum, cursor,
                                           csr_src, as1, ad1, wls, E);
  aggregate1_kernel<<<(N + 3) / 4, 256, 0, stream>>>(
      h1b, as1, ad1, offsets, bsum, csr_src, wls, b1, vs, vd, h2b, as2, ad2, N);
  mfma_gemm<64, false><<<dim3(DOUT / 128, M_PAD / 64), 256, 0, stream>>>(
      h2b, W2T, t2b, N, DOUT, HID1, nullptr, nullptr, nullptr, nullptr);
  aggregate2_kernel<<<(N + 3) / 4, 256, 0, stream>>>(
      t2b, as2, ad2, offsets, bsum, csr_src, b2v, out, N);
}

// Round 12
// 346.342 us; speedup vs baseline: 1.1685x; 1.1100x over previous
//
#include <hip/hip_runtime.h>

// N=20000, E=640000, D_IN=256, HID1=512 (4 heads x 128), D_OUT=128, R=32.
// fp32 in/out; internal bf16. Key identity: GEMM commutes with aggregation —
// aggregate x_mod rows (512B) per head, THEN gemm1; logits as1/ad1 computed
// directly from x_mod via u=W1*att (fused into xmod); gemm1 epilogue fuses
// bias+ELU+as2/ad2 dots. h1 never materialized. 8 kernels.

#define D_IN   256
#define HID1   512
#define NHEADS 4
#define DOUT   128
#define NREL   32
#define NEG_SLOPE 0.2f
#define M_PAD  20096   // 157*128 == 314*64

static __device__ __forceinline__ unsigned short f2b(float f) {
  union { float f; unsigned int i; } v; v.f = f;
  unsigned int x = v.i;
  return (unsigned short)((x + 0x7fffu + ((x >> 16) & 1u)) >> 16);
}
static __device__ __forceinline__ float lrelu(float x) {
  return x > 0.f ? x : NEG_SLOPE * x;
}
static __device__ __forceinline__ void acc8(float* acc, float w, uint4 r) {
  unsigned int u;
  union { unsigned int i; float f; } cl, ch;
  u = r.x; cl.i = u << 16; ch.i = u & 0xffff0000u; acc[0] += w * cl.f; acc[1] += w * ch.f;
  u = r.y; cl.i = u << 16; ch.i = u & 0xffff0000u; acc[2] += w * cl.f; acc[3] += w * ch.f;
  u = r.z; cl.i = u << 16; ch.i = u & 0xffff0000u; acc[4] += w * cl.f; acc[5] += w * ch.f;
  u = r.w; cl.i = u << 16; ch.i = u & 0xffff0000u; acc[6] += w * cl.f; acc[7] += w * ch.f;
}

typedef __attribute__((ext_vector_type(8))) short bf16x8;
typedef __attribute__((ext_vector_type(4))) float f32x4;

// ---- prep: edge counts + weight casts + u/vs/vd precompute ----------------
__global__ void prep_kernel(const int* __restrict__ src, const int* __restrict__ dst,
                            const int* __restrict__ et, int* __restrict__ counts,
                            int* __restrict__ deg, int E, int eb, int cb,
                            const float* __restrict__ W1, const float* __restrict__ W2,
                            unsigned short* __restrict__ W1T, unsigned short* __restrict__ W2T,
                            const float* __restrict__ att_s1, const float* __restrict__ att_d1,
                            float* __restrict__ us4, float* __restrict__ ud4,
                            const float* __restrict__ att_s2, const float* __restrict__ att_d2,
                            float* __restrict__ vs, float* __restrict__ vd) {
  int b = blockIdx.x;
  int t = threadIdx.x;
  if (b < eb) {
    int e = b * 256 + t;
    if (e >= E) return;
    atomicAdd(&counts[(size_t)src[e] * NREL + et[e]], 1);
    atomicAdd(&deg[dst[e]], 1);
  } else if (b < eb + cb) {
    int idx = (b - eb) * 256 + t;
    if (idx < D_IN * HID1) {
      int r = idx / HID1, c = idx % HID1;
      W1T[(size_t)c * D_IN + r] = f2b(W1[idx]);
    } else {
      int k = idx - D_IN * HID1;
      if (k < HID1 * DOUT) {
        int r = k / DOUT, c = k % DOUT;
        W2T[(size_t)c * HID1 + r] = f2b(W2[k]);
      }
    }
  } else if (b == eb + cb) {
    // u tables: us4[k][h] = sum_c W1[k][h*128+c]*att_s1[h*128+c]
    int k = t;  // 0..255
    float us[4] = {0.f, 0.f, 0.f, 0.f}, ud[4] = {0.f, 0.f, 0.f, 0.f};
    for (int h = 0; h < 4; ++h)
      for (int c = 0; c < 128; ++c) {
        float wv = W1[(size_t)k * HID1 + h * 128 + c];
        us[h] += wv * att_s1[h * 128 + c];
        ud[h] += wv * att_d1[h * 128 + c];
      }
    ((float4*)us4)[k] = make_float4(us[0], us[1], us[2], us[3]);
    ((float4*)ud4)[k] = make_float4(ud[0], ud[1], ud[2], ud[3]);
  } else {
    // vs/vd: vs[r] = sum_c W2[r][c]*att_s2[c]
#pragma unroll
    for (int rr = 0; rr < 2; ++rr) {
      int r = t * 2 + rr;  // 0..511
      float ss = 0.f, dd = 0.f;
      for (int c = 0; c < DOUT; ++c) {
        float wv = W2[(size_t)r * DOUT + c];
        ss += wv * att_s2[c];
        dd += wv * att_d2[c];
      }
      vs[r] = ss; vd[r] = dd;
    }
  }
}

// ---- scan -----------------------------------------------------------------
__global__ void scan_local(const int* __restrict__ in, int* __restrict__ out,
                           int* __restrict__ bsum, int n) {
  __shared__ int wsum[4];
  int t = threadIdx.x;
  int base = blockIdx.x * 1024 + t * 4;
  int v0 = (base + 0 < n) ? in[base + 0] : 0;
  int v1 = (base + 1 < n) ? in[base + 1] : 0;
  int v2 = (base + 2 < n) ? in[base + 2] : 0;
  int v3 = (base + 3 < n) ? in[base + 3] : 0;
  int s = v0 + v1 + v2 + v3;
  int lane = t & 63, w = t >> 6;
  int sc = s;
  for (int off = 1; off < 64; off <<= 1) {
    int u = __shfl_up(sc, off);
    if (lane >= off) sc += u;
  }
  if (lane == 63) wsum[w] = sc;
  __syncthreads();
  int woff = 0;
  for (int i = 0; i < w; ++i) woff += wsum[i];
  int excl = woff + sc - s;
  if (base + 0 < n) out[base + 0] = excl;
  if (base + 1 < n) out[base + 1] = excl + v0;
  if (base + 2 < n) out[base + 2] = excl + v0 + v1;
  if (base + 3 < n) out[base + 3] = excl + v0 + v1 + v2;
  if (t == 255) bsum[blockIdx.x] = woff + sc;
}

__global__ void scan_blocks(int* __restrict__ bsum, int nb,
                            int* __restrict__ offsets, int n) {
  int t = threadIdx.x;  // 64
  int v = (t < nb) ? bsum[t] : 0;
  int sc = v;
  for (int off = 1; off < 64; off <<= 1) {
    int u = __shfl_up(sc, off);
    if (t >= off) sc += u;
  }
  if (t < nb) bsum[t] = sc - v;
  if (t == nb - 1) offsets[n] = v;
}

__global__ void scatter_kernel(const int* __restrict__ src, const int* __restrict__ dst,
                               const int* __restrict__ offsets, const int* __restrict__ bsum,
                               int* __restrict__ cursor, int* __restrict__ csr_src, int E) {
  int e = blockIdx.x * 256 + threadIdx.x;
  if (e >= E) return;
  int d = dst[e];
  int pos = offsets[d] + bsum[d >> 10] + atomicAdd(&cursor[d], 1);
  csr_src[pos] = src[e];
}

// ---- x_mod + fused logits as1/ad1 -----------------------------------------
__global__ __launch_bounds__(256) void xmod_kernel(
    const float* __restrict__ x, const int* __restrict__ counts,
    const float* __restrict__ rel, const float* __restrict__ us4,
    const float* __restrict__ ud4, unsigned short* __restrict__ x_modb,
    float* __restrict__ as1, float* __restrict__ ad1, int n_nodes) {
  int wv = threadIdx.x >> 6;
  int node = blockIdx.x * 4 + wv;
  if (node >= n_nodes) return;
  int l = threadIdx.x & 63;
  int cnt_l = counts[(size_t)node * NREL + (l & 31)];
  const float4* x4 = (const float4*)x;
  const float4* rel4 = (const float4*)rel;
  float4 v = x4[(size_t)node * 64 + l];
#pragma unroll
  for (int r = 0; r < NREL; ++r) {
    int c = __shfl(cnt_l, r);  // wave-uniform
    if (c) {
      float4 rv = rel4[r * 64 + l];
      float fc = (float)c;
      v.x += fc * rv.x; v.y += fc * rv.y; v.z += fc * rv.z; v.w += fc * rv.w;
    }
  }
  ushort4 o;
  o.x = f2b(v.x); o.y = f2b(v.y); o.z = f2b(v.z); o.w = f2b(v.w);
  *(ushort4*)(x_modb + (size_t)node * D_IN + l * 4) = o;
  // logits: as1[node][h] = sum_k x_mod[k]*us4[k][h]
  const float4* usv = (const float4*)us4;
  const float4* udv = (const float4*)ud4;
  float vv[4] = {v.x, v.y, v.z, v.w};
  float sh[4] = {0.f, 0.f, 0.f, 0.f}, dh[4] = {0.f, 0.f, 0.f, 0.f};
#pragma unroll
  for (int i = 0; i < 4; ++i) {
    float4 uu = usv[l * 4 + i];
    float4 dd = udv[l * 4 + i];
    sh[0] += vv[i] * uu.x; sh[1] += vv[i] * uu.y; sh[2] += vv[i] * uu.z; sh[3] += vv[i] * uu.w;
    dh[0] += vv[i] * dd.x; dh[1] += vv[i] * dd.y; dh[2] += vv[i] * dd.z; dh[3] += vv[i] * dd.w;
  }
  for (int off = 32; off; off >>= 1) {
#pragma unroll
    for (int h = 0; h < 4; ++h) {
      sh[h] += __shfl_xor(sh[h], off);
      dh[h] += __shfl_xor(dh[h], off);
    }
  }
  if (l == 0) {
    ((float4*)as1)[node] = make_float4(sh[0], sh[1], sh[2], sh[3]);
    ((float4*)ad1)[node] = make_float4(dh[0], dh[1], dh[2], dh[3]);
  }
}

// ---- layer-1 aggregate over x_mod rows (512B), per-head -------------------
// one wave/node; h = lane>>4; l16 covers ch [16*l16..16*l16+15] of 256.
__global__ __launch_bounds__(256) void aggregate1_kernel(
    const unsigned short* __restrict__ x_modb,
    const float* __restrict__ as1, const float* __restrict__ ad1,
    const int* __restrict__ offsets, const int* __restrict__ bsum,
    const int* __restrict__ csr_src,
    unsigned short* __restrict__ agg_xb, int n_nodes) {
  int node = blockIdx.x * 4 + (threadIdx.x >> 6);
  if (node >= n_nodes) return;
  int lane = threadIdx.x & 63;
  int h = lane >> 4, l16 = lane & 15;
  int lo = offsets[node] + bsum[node >> 10];
  int hi = offsets[node + 1] + bsum[(node + 1) >> 10];
  float ad_own = ad1[node * 4 + h];

  const uint4* xv = (const uint4*)x_modb;  // 32 uint4 per row
  float acc[16];
#pragma unroll
  for (int k = 0; k < 16; ++k) acc[k] = 0.f;
  float denom = 0.f;

  int n_it = hi - lo;
  int j = lo;
  int s = (j < hi) ? csr_src[j] : node;
  float asv = as1[s * 4 + h];  // pipelined 1 ahead
  for (int i = 0; i < n_it; ++i) {
    int jn = j + 1;
    int sn = (jn < hi) ? csr_src[jn] : node;
    float asn = as1[sn * 4 + h];
    uint4 r0 = xv[(size_t)s * 32 + l16 * 2];
    uint4 r1 = xv[(size_t)s * 32 + l16 * 2 + 1];
    float w = __expf(lrelu(asv + ad_own));
    acc8(acc, w, r0); acc8(acc + 8, w, r1);
    denom += w;
    j = jn; s = sn; asv = asn;
  }
  { // self loop
    float w = __expf(lrelu(as1[node * 4 + h] + ad_own));
    uint4 r0 = xv[(size_t)node * 32 + l16 * 2];
    uint4 r1 = xv[(size_t)node * 32 + l16 * 2 + 1];
    acc8(acc, w, r0); acc8(acc + 8, w, r1);
    denom += w;
  }
  float inv = 1.f / (denom + 1e-16f);
  unsigned int od[8];
#pragma unroll
  for (int q = 0; q < 8; ++q)
    od[q] = (unsigned int)f2b(acc[2 * q] * inv) |
            ((unsigned int)f2b(acc[2 * q + 1] * inv) << 16);
  unsigned short* outp = agg_xb + ((size_t)h * M_PAD + node) * D_IN + l16 * 16;
  uint4 o0; o0.x = od[0]; o0.y = od[1]; o0.z = od[2]; o0.w = od[3];
  uint4 o1; o1.x = od[4]; o1.y = od[5]; o1.z = od[6]; o1.w = od[7];
  *(uint4*)outp = o0;
  *(uint4*)(outp + 8) = o1;
}

// ---- bf16 MFMA GEMM. MODE 1: per-head A slice + bias/ELU/as2-ad2 epilogue -
template <int BM, int MODE>
__global__ __launch_bounds__(256) void mfma_gemm(
    const unsigned short* __restrict__ A, const unsigned short* __restrict__ BT,
    unsigned short* __restrict__ C, int M, int N, int K,
    const float* __restrict__ bias, const float* __restrict__ vs,
    const float* __restrict__ vd, float* __restrict__ as2, float* __restrict__ ad2) {
  constexpr int MFR = BM / 32;
  __shared__ __align__(16) unsigned short Asl[BM * 32];
  __shared__ __align__(16) unsigned short Bsl[128 * 32];
  int tid = threadIdx.x;
  int m0 = blockIdx.y * BM, n0 = blockIdx.x * 128;
  int lane = tid & 63, wv = tid >> 6;
  int wm = wv & 1, wn = wv >> 1;
  int l16 = lane & 15, quad = lane >> 4;
  int lr = lane >> 2, lseg = lane & 3;
  if (MODE == 1) A += (size_t)blockIdx.x * M_PAD * K;  // head slice

  f32x4 acc[MFR][4];
#pragma unroll
  for (int i = 0; i < MFR; ++i)
#pragma unroll
    for (int j = 0; j < 4; ++j) acc[i][j] = (f32x4)(0.f);

  for (int k0 = 0; k0 < K; k0 += 32) {
#pragma unroll
    for (int c = wv; c < BM / 16; c += 4) {
      int gr = m0 + c * 16 + lr; gr = gr < M ? gr : M - 1;
      __builtin_amdgcn_global_load_lds(
          (const __attribute__((address_space(1))) void*)(A + (size_t)gr * K + k0 + lseg * 8),
          (__attribute__((address_space(3))) void*)(&Asl[c * 512]), 16, 0, 0);
    }
#pragma unroll
    for (int c = wv; c < 8; c += 4) {
      int gr = n0 + c * 16 + lr;
      __builtin_amdgcn_global_load_lds(
          (const __attribute__((address_space(1))) void*)(BT + (size_t)gr * K + k0 + lseg * 8),
          (__attribute__((address_space(3))) void*)(&Bsl[c * 512]), 16, 0, 0);
    }
    __syncthreads();
    bf16x8 af[MFR], bfr[4];
#pragma unroll
    for (int mf = 0; mf < MFR; ++mf)
      af[mf] = *(const bf16x8*)(&Asl[(wm * (BM / 2) + mf * 16 + l16) * 32 + quad * 8]);
#pragma unroll
    for (int nf = 0; nf < 4; ++nf)
      bfr[nf] = *(const bf16x8*)(&Bsl[(wn * 64 + nf * 16 + l16) * 32 + quad * 8]);
#pragma unroll
    for (int mf = 0; mf < MFR; ++mf)
#pragma unroll
      for (int nf = 0; nf < 4; ++nf)
        acc[mf][nf] = __builtin_amdgcn_mfma_f32_16x16x32_bf16(af[mf], bfr[nf], acc[mf][nf], 0, 0, 0);
    __syncthreads();
  }
  if (MODE == 0) {
#pragma unroll
    for (int mf = 0; mf < MFR; ++mf)
#pragma unroll
      for (int nf = 0; nf < 4; ++nf)
#pragma unroll
        for (int r = 0; r < 4; ++r) {
          int row = m0 + wm * (BM / 2) + mf * 16 + quad * 4 + r;
          int col = n0 + wn * 64 + nf * 16 + l16;
          C[(size_t)row * N + col] = f2b(acc[mf][nf][r]);
        }
  } else {
#pragma unroll
    for (int mf = 0; mf < MFR; ++mf)
#pragma unroll
      for (int r = 0; r < 4; ++r) {
        int row = m0 + wm * (BM / 2) + mf * 16 + quad * 4 + r;
        float sd = 0.f, dd = 0.f;
#pragma unroll
        for (int nf = 0; nf < 4; ++nf) {
          int col = n0 + wn * 64 + nf * 16 + l16;
          float cv = acc[mf][nf][r] + bias[col];
          cv = cv > 0.f ? cv : expm1f(cv);  // ELU
          C[(size_t)row * N + col] = f2b(cv);
          sd += cv * vs[col];
          dd += cv * vd[col];
        }
#pragma unroll
        for (int off = 1; off < 16; off <<= 1) {
          sd += __shfl_xor(sd, off);
          dd += __shfl_xor(dd, off);
        }
        if (l16 == 0 && row < M) {
          atomicAdd(&as2[row], sd);
          atomicAdd(&ad2[row], dd);
        }
      }
  }
}

// ---- layer-2 aggregate: one wave/node, 4 groups, pipelined ---------------
__global__ __launch_bounds__(256) void aggregate2_kernel(
    const unsigned short* __restrict__ t2b,
    const float* __restrict__ as2, const float* __restrict__ ad2,
    const int* __restrict__ offsets, const int* __restrict__ bsum,
    const int* __restrict__ csr_src,
    const float* __restrict__ bias, float* __restrict__ out, int n_nodes) {
  int node = blockIdx.x * 4 + (threadIdx.x >> 6);
  if (node >= n_nodes) return;
  int lane = threadIdx.x & 63;
  int g = lane >> 4, l16 = lane & 15;
  int lo = offsets[node] + bsum[node >> 10];
  int hi = offsets[node + 1] + bsum[(node + 1) >> 10];
  float ad = ad2[node];

  const uint4* t2v = (const uint4*)t2b;
  float acc[8] = {0.f, 0.f, 0.f, 0.f, 0.f, 0.f, 0.f, 0.f};
  float denom = 0.f;
  int nit = (hi - lo + 3) >> 2;
  int j = lo + g;
  bool valid = j < hi;
  int s = valid ? csr_src[j] : node;
  float asv = as2[s];
  for (int i = 0; i < nit; ++i) {
    int jn = j + 4;
    bool vn = jn < hi;
    int sn = vn ? csr_src[jn] : node;
    float asv_n = as2[sn];
    uint4 tv = t2v[(size_t)s * 16 + l16];
    float w = valid ? __expf(lrelu(asv + ad)) : 0.f;
    acc8(acc, w, tv);
    denom += w;
    j = jn; valid = vn; s = sn; asv = asv_n;
  }
  if (g == 0) {  // self loop
    uint4 tv = t2v[(size_t)node * 16 + l16];
    float w = __expf(lrelu(as2[node] + ad));
    acc8(acc, w, tv);
    denom += w;
  }
#pragma unroll
  for (int k = 0; k < 8; ++k) {
    acc[k] += __shfl_xor(acc[k], 16);
    acc[k] += __shfl_xor(acc[k], 32);
  }
  denom += __shfl_xor(denom, 16);
  denom += __shfl_xor(denom, 32);
  if (g == 0) {
    float inv = 1.f / (denom + 1e-16f);
    float4 o0, o1;
    o0.x = acc[0] * inv + bias[l16 * 8 + 0];
    o0.y = acc[1] * inv + bias[l16 * 8 + 1];
    o0.z = acc[2] * inv + bias[l16 * 8 + 2];
    o0.w = acc[3] * inv + bias[l16 * 8 + 3];
    o1.x = acc[4] * inv + bias[l16 * 8 + 4];
    o1.y = acc[5] * inv + bias[l16 * 8 + 5];
    o1.z = acc[6] * inv + bias[l16 * 8 + 6];
    o1.w = acc[7] * inv + bias[l16 * 8 + 7];
    *(float4*)(out + (size_t)node * DOUT + l16 * 8) = o0;
    *(float4*)(out + (size_t)node * DOUT + l16 * 8 + 4) = o1;
  }
}

extern "C" void kernel_launch(void* const* d_in, const int* in_sizes, int n_in,
                              void* d_out, int out_size, void* d_ws, size_t ws_size,
                              hipStream_t stream) {
  const float* x     = (const float*)d_in[0];
  const int* ei      = (const int*)d_in[1];
  const int* etype   = (const int*)d_in[2];
  const float* rel   = (const float*)d_in[3];
  const float* W1    = (const float*)d_in[4];
  const float* at_s1 = (const float*)d_in[5];
  const float* at_d1 = (const float*)d_in[6];
  const float* b1    = (const float*)d_in[7];
  const float* W2    = (const float*)d_in[8];
  const float* at_s2 = (const float*)d_in[9];
  const float* at_d2 = (const float*)d_in[10];
  const float* b2v   = (const float*)d_in[11];
  float* out         = (float*)d_out;

  const int N = in_sizes[0] / D_IN;  // 20000
  const int E = in_sizes[2];         // 640000
  const int* srcv = ei;
  const int* dstv = ei + E;

  char* p = (char*)d_ws;
  auto carve = [&](size_t bytes) -> char* {
    char* r = p; p += (bytes + 255) & ~(size_t)255; return r;
  };
  // zeroed region (counters + as2/ad2 atomic accumulators)
  int*   counts  = (int*)carve((size_t)N * NREL * 4);
  int*   deg     = (int*)carve((size_t)N * 4);
  int*   offsets = (int*)carve(((size_t)N + 1) * 4);
  int*   cursor  = (int*)carve((size_t)N * 4);
  int*   bsum    = (int*)carve(64 * 4);
  float* as2     = (float*)carve((size_t)N * 4);
  float* ad2     = (float*)carve((size_t)N * 4);
  size_t zero_bytes = (size_t)(p - (char*)counts);
  // plain scratch
  float* as1     = (float*)carve((size_t)N * NHEADS * 4);
  float* ad1     = (float*)carve((size_t)N * NHEADS * 4);
  float* vs      = (float*)carve((size_t)HID1 * 4);
  float* vd      = (float*)carve((size_t)HID1 * 4);
  float* us4     = (float*)carve((size_t)D_IN * 4 * 4);
  float* ud4     = (float*)carve((size_t)D_IN * 4 * 4);
  int*   csr_src = (int*)carve((size_t)E * 4);
  unsigned short* W1T    = (unsigned short*)carve((size_t)HID1 * D_IN * 2);
  unsigned short* W2T    = (unsigned short*)carve((size_t)DOUT * HID1 * 2);
  unsigned short* x_modb = (unsigned short*)carve((size_t)N * D_IN * 2);
  unsigned short* agg_xb = (unsigned short*)carve((size_t)NHEADS * M_PAD * D_IN * 2);
  unsigned short* h2b    = (unsigned short*)carve((size_t)M_PAD * HID1 * 2);
  unsigned short* t2b    = (unsigned short*)carve((size_t)M_PAD * DOUT * 2);

  hipMemsetAsync(counts, 0, zero_bytes, stream);

  int eb = (E + 255) / 256;                          // 2500
  int cb = (D_IN * HID1 + HID1 * DOUT + 255) / 256;  // 768
  int nb = (N + 1023) / 1024;                        // 20
  prep_kernel<<<eb + cb + 2, 256, 0, stream>>>(srcv, dstv, etype, counts, deg, E, eb, cb,
                                               W1, W2, W1T, W2T, at_s1, at_d1, us4, ud4,
                                               at_s2, at_d2, vs, vd);
  scan_local<<<nb, 256, 0, stream>>>(deg, offsets, bsum, N);
  scan_blocks<<<1, 64, 0, stream>>>(bsum, nb, offsets, N);
  scatter_kernel<<<eb, 256, 0, stream>>>(srcv, dstv, offsets, bsum, cursor, csr_src, E);
  xmod_kernel<<<(N + 3) / 4, 256, 0, stream>>>(x, counts, rel, us4, ud4, x_modb, as1, ad1, N);
  aggregate1_kernel<<<(N + 3) / 4, 256, 0, stream>>>(x_modb, as1, ad1, offsets, bsum,
                                                     csr_src, agg_xb, N);
  mfma_gemm<128, 1><<<dim3(NHEADS, M_PAD / 128), 256, 0, stream>>>(
      agg_xb, W1T, h2b, N, HID1, D_IN, b1, vs, vd, as2, ad2);
  mfma_gemm<64, 0><<<dim3(DOUT / 128, M_PAD / 64), 256, 0, stream>>>(
      h2b, W2T, t2b, N, DOUT, HID1, nullptr, nullptr, nullptr, nullptr, nullptr);
  aggregate2_kernel<<<(N + 3) / 4, 256, 0, stream>>>(
      t2b, as2, ad2, offsets, bsum, csr_src, b2v, out, N);
}

// Round 13
// 341.562 us; speedup vs baseline: 1.1849x; 1.0140x over previous
//
#include <hip/hip_runtime.h>

// N=20000, E=640000, D_IN=256, HID1=512 (4 heads x 128), D_OUT=128, R=32.
// fp32 in/out; internal bf16. GEMM commuted past aggregation (agg over 512B
// x_mod rows). agg1: head-pair layout (row read once per half-wave) + packed
// v_pk_fma_f32 accumulation. 8 kernels.

#define D_IN   256
#define HID1   512
#define NHEADS 4
#define DOUT   128
#define NREL   32
#define NEG_SLOPE 0.2f
#define M_PAD  20096   // 157*128 == 314*64

static __device__ __forceinline__ unsigned short f2b(float f) {
  union { float f; unsigned int i; } v; v.f = f;
  unsigned int x = v.i;
  return (unsigned short)((x + 0x7fffu + ((x >> 16) & 1u)) >> 16);
}
static __device__ __forceinline__ float lrelu(float x) {
  return x > 0.f ? x : NEG_SLOPE * x;
}

typedef __attribute__((ext_vector_type(8))) short bf16x8;
typedef __attribute__((ext_vector_type(4))) float f32x4;
typedef __attribute__((ext_vector_type(2))) float f32x2;

// unpack dword (2 bf16) -> f32x2
static __device__ __forceinline__ f32x2 up2(unsigned int u) {
  union { unsigned int i; float f; } lo, hi;
  lo.i = u << 16; hi.i = u & 0xffff0000u;
  f32x2 v; v.x = lo.f; v.y = hi.f; return v;
}
// packed acc: acc[0..3] (f32x2 each) += w * (8 bf16 in uint4)
static __device__ __forceinline__ void accp(f32x2* acc, float w, uint4 r) {
  f32x2 wv = (f32x2)(w);
  acc[0] += wv * up2(r.x);
  acc[1] += wv * up2(r.y);
  acc[2] += wv * up2(r.z);
  acc[3] += wv * up2(r.w);
}

// ---- prep: edge counts + weight casts + u/vs/vd precompute ----------------
__global__ void prep_kernel(const int* __restrict__ src, const int* __restrict__ dst,
                            const int* __restrict__ et, int* __restrict__ counts,
                            int* __restrict__ deg, int E, int eb, int cb,
                            const float* __restrict__ W1, const float* __restrict__ W2,
                            unsigned short* __restrict__ W1T, unsigned short* __restrict__ W2T,
                            const float* __restrict__ att_s1, const float* __restrict__ att_d1,
                            float* __restrict__ us4, float* __restrict__ ud4,
                            const float* __restrict__ att_s2, const float* __restrict__ att_d2,
                            float* __restrict__ vs, float* __restrict__ vd) {
  int b = blockIdx.x;
  int t = threadIdx.x;
  if (b < eb) {
    int e = b * 256 + t;
    if (e >= E) return;
    atomicAdd(&counts[(size_t)src[e] * NREL + et[e]], 1);
    atomicAdd(&deg[dst[e]], 1);
  } else if (b < eb + cb) {
    int idx = (b - eb) * 256 + t;
    if (idx < D_IN * HID1) {
      int r = idx / HID1, c = idx % HID1;
      W1T[(size_t)c * D_IN + r] = f2b(W1[idx]);
    } else {
      int k = idx - D_IN * HID1;
      if (k < HID1 * DOUT) {
        int r = k / DOUT, c = k % DOUT;
        W2T[(size_t)c * HID1 + r] = f2b(W2[k]);
      }
    }
  } else if (b == eb + cb) {
    int k = t;  // 0..255
    float us[4] = {0.f, 0.f, 0.f, 0.f}, ud[4] = {0.f, 0.f, 0.f, 0.f};
    for (int h = 0; h < 4; ++h)
      for (int c = 0; c < 128; ++c) {
        float wv = W1[(size_t)k * HID1 + h * 128 + c];
        us[h] += wv * att_s1[h * 128 + c];
        ud[h] += wv * att_d1[h * 128 + c];
      }
    ((float4*)us4)[k] = make_float4(us[0], us[1], us[2], us[3]);
    ((float4*)ud4)[k] = make_float4(ud[0], ud[1], ud[2], ud[3]);
  } else {
#pragma unroll
    for (int rr = 0; rr < 2; ++rr) {
      int r = t * 2 + rr;  // 0..511
      float ss = 0.f, dd = 0.f;
      for (int c = 0; c < DOUT; ++c) {
        float wv = W2[(size_t)r * DOUT + c];
        ss += wv * att_s2[c];
        dd += wv * att_d2[c];
      }
      vs[r] = ss; vd[r] = dd;
    }
  }
}

// ---- scan -----------------------------------------------------------------
__global__ void scan_local(const int* __restrict__ in, int* __restrict__ out,
                           int* __restrict__ bsum, int n) {
  __shared__ int wsum[4];
  int t = threadIdx.x;
  int base = blockIdx.x * 1024 + t * 4;
  int v0 = (base + 0 < n) ? in[base + 0] : 0;
  int v1 = (base + 1 < n) ? in[base + 1] : 0;
  int v2 = (base + 2 < n) ? in[base + 2] : 0;
  int v3 = (base + 3 < n) ? in[base + 3] : 0;
  int s = v0 + v1 + v2 + v3;
  int lane = t & 63, w = t >> 6;
  int sc = s;
  for (int off = 1; off < 64; off <<= 1) {
    int u = __shfl_up(sc, off);
    if (lane >= off) sc += u;
  }
  if (lane == 63) wsum[w] = sc;
  __syncthreads();
  int woff = 0;
  for (int i = 0; i < w; ++i) woff += wsum[i];
  int excl = woff + sc - s;
  if (base + 0 < n) out[base + 0] = excl;
  if (base + 1 < n) out[base + 1] = excl + v0;
  if (base + 2 < n) out[base + 2] = excl + v0 + v1;
  if (base + 3 < n) out[base + 3] = excl + v0 + v1 + v2;
  if (t == 255) bsum[blockIdx.x] = woff + sc;
}

__global__ void scan_blocks(int* __restrict__ bsum, int nb,
                            int* __restrict__ offsets, int n) {
  int t = threadIdx.x;  // 64
  int v = (t < nb) ? bsum[t] : 0;
  int sc = v;
  for (int off = 1; off < 64; off <<= 1) {
    int u = __shfl_up(sc, off);
    if (t >= off) sc += u;
  }
  if (t < nb) bsum[t] = sc - v;
  if (t == nb - 1) offsets[n] = v;
}

__global__ void scatter_kernel(const int* __restrict__ src, const int* __restrict__ dst,
                               const int* __restrict__ offsets, const int* __restrict__ bsum,
                               int* __restrict__ cursor, int* __restrict__ csr_src, int E) {
  int e = blockIdx.x * 256 + threadIdx.x;
  if (e >= E) return;
  int d = dst[e];
  int pos = offsets[d] + bsum[d >> 10] + atomicAdd(&cursor[d], 1);
  csr_src[pos] = src[e];
}

// ---- x_mod + fused logits as1/ad1 -----------------------------------------
__global__ __launch_bounds__(256) void xmod_kernel(
    const float* __restrict__ x, const int* __restrict__ counts,
    const float* __restrict__ rel, const float* __restrict__ us4,
    const float* __restrict__ ud4, unsigned short* __restrict__ x_modb,
    float* __restrict__ as1, float* __restrict__ ad1, int n_nodes) {
  int wv = threadIdx.x >> 6;
  int node = blockIdx.x * 4 + wv;
  if (node >= n_nodes) return;
  int l = threadIdx.x & 63;
  int cnt_l = counts[(size_t)node * NREL + (l & 31)];
  const float4* x4 = (const float4*)x;
  const float4* rel4 = (const float4*)rel;
  float4 v = x4[(size_t)node * 64 + l];
#pragma unroll
  for (int r = 0; r < NREL; ++r) {
    int c = __shfl(cnt_l, r);  // wave-uniform
    if (c) {
      float4 rv = rel4[r * 64 + l];
      float fc = (float)c;
      v.x += fc * rv.x; v.y += fc * rv.y; v.z += fc * rv.z; v.w += fc * rv.w;
    }
  }
  ushort4 o;
  o.x = f2b(v.x); o.y = f2b(v.y); o.z = f2b(v.z); o.w = f2b(v.w);
  *(ushort4*)(x_modb + (size_t)node * D_IN + l * 4) = o;
  const float4* usv = (const float4*)us4;
  const float4* udv = (const float4*)ud4;
  float vv[4] = {v.x, v.y, v.z, v.w};
  float sh[4] = {0.f, 0.f, 0.f, 0.f}, dh[4] = {0.f, 0.f, 0.f, 0.f};
#pragma unroll
  for (int i = 0; i < 4; ++i) {
    float4 uu = usv[l * 4 + i];
    float4 dd = udv[l * 4 + i];
    sh[0] += vv[i] * uu.x; sh[1] += vv[i] * uu.y; sh[2] += vv[i] * uu.z; sh[3] += vv[i] * uu.w;
    dh[0] += vv[i] * dd.x; dh[1] += vv[i] * dd.y; dh[2] += vv[i] * dd.z; dh[3] += vv[i] * dd.w;
  }
  for (int off = 32; off; off >>= 1) {
#pragma unroll
    for (int h = 0; h < 4; ++h) {
      sh[h] += __shfl_xor(sh[h], off);
      dh[h] += __shfl_xor(dh[h], off);
    }
  }
  if (l == 0) {
    ((float4*)as1)[node] = make_float4(sh[0], sh[1], sh[2], sh[3]);
    ((float4*)ad1)[node] = make_float4(dh[0], dh[1], dh[2], dh[3]);
  }
}

// ---- layer-1 aggregate over x_mod rows, head-pair layout ------------------
// one wave/node; hp = lane>>5 handles heads {2hp, 2hp+1}; l32 covers 8 ch.
__global__ __launch_bounds__(256) void aggregate1_kernel(
    const unsigned short* __restrict__ x_modb,
    const float* __restrict__ as1, const float* __restrict__ ad1,
    const int* __restrict__ offsets, const int* __restrict__ bsum,
    const int* __restrict__ csr_src,
    unsigned short* __restrict__ agg_xb, int n_nodes) {
  int node = blockIdx.x * 4 + (threadIdx.x >> 6);
  if (node >= n_nodes) return;
  int lane = threadIdx.x & 63;
  int hp = lane >> 5, l32 = lane & 31;
  int lo = offsets[node] + bsum[node >> 10];
  int hi = offsets[node + 1] + bsum[(node + 1) >> 10];
  float2 adp = *(const float2*)(ad1 + (size_t)node * 4 + 2 * hp);
  float2 asp = *(const float2*)(as1 + (size_t)node * 4 + 2 * hp);

  const uint4* xv = (const uint4*)x_modb;  // 32 uint4 per 512B row
  f32x2 acc0[4], acc1[4];                  // head 2hp, head 2hp+1
#pragma unroll
  for (int k = 0; k < 4; ++k) { acc0[k] = (f32x2)(0.f); acc1[k] = (f32x2)(0.f); }
  f32x2 den = (f32x2)(0.f);

  int n_it = hi - lo;
  int j = lo;
  int s = (j < hi) ? csr_src[j] : node;
  float2 av = *(const float2*)(as1 + (size_t)s * 4 + 2 * hp);  // 1-ahead
  for (int i = 0; i < n_it; ++i) {
    int jn = j + 1;
    int sn = (jn < hi) ? csr_src[jn] : node;
    float2 avn = *(const float2*)(as1 + (size_t)sn * 4 + 2 * hp);
    uint4 r = xv[(size_t)s * 32 + l32];
    float w0 = __expf(lrelu(av.x + adp.x));
    float w1 = __expf(lrelu(av.y + adp.y));
    accp(acc0, w0, r);
    accp(acc1, w1, r);
    den.x += w0; den.y += w1;
    j = jn; s = sn; av = avn;
  }
  { // self loop
    uint4 r = xv[(size_t)node * 32 + l32];
    float w0 = __expf(lrelu(asp.x + adp.x));
    float w1 = __expf(lrelu(asp.y + adp.y));
    accp(acc0, w0, r);
    accp(acc1, w1, r);
    den.x += w0; den.y += w1;
  }
  float inv0 = 1.f / (den.x + 1e-16f);
  float inv1 = 1.f / (den.y + 1e-16f);
  unsigned int od0[4], od1[4];
#pragma unroll
  for (int p = 0; p < 4; ++p) {
    od0[p] = (unsigned int)f2b(acc0[p].x * inv0) | ((unsigned int)f2b(acc0[p].y * inv0) << 16);
    od1[p] = (unsigned int)f2b(acc1[p].x * inv1) | ((unsigned int)f2b(acc1[p].y * inv1) << 16);
  }
  uint4 o0; o0.x = od0[0]; o0.y = od0[1]; o0.z = od0[2]; o0.w = od0[3];
  uint4 o1; o1.x = od1[0]; o1.y = od1[1]; o1.z = od1[2]; o1.w = od1[3];
  *(uint4*)(agg_xb + ((size_t)(2 * hp) * M_PAD + node) * D_IN + l32 * 8) = o0;
  *(uint4*)(agg_xb + ((size_t)(2 * hp + 1) * M_PAD + node) * D_IN + l32 * 8) = o1;
}

// ---- bf16 MFMA GEMM. MODE 1: per-head A slice + bias/ELU/as2-ad2 epilogue -
template <int BM, int MODE>
__global__ __launch_bounds__(256) void mfma_gemm(
    const unsigned short* __restrict__ A, const unsigned short* __restrict__ BT,
    unsigned short* __restrict__ C, int M, int N, int K,
    const float* __restrict__ bias, const float* __restrict__ vs,
    const float* __restrict__ vd, float* __restrict__ as2, float* __restrict__ ad2) {
  constexpr int MFR = BM / 32;
  __shared__ __align__(16) unsigned short Asl[BM * 32];
  __shared__ __align__(16) unsigned short Bsl[128 * 32];
  int tid = threadIdx.x;
  int m0 = blockIdx.y * BM, n0 = blockIdx.x * 128;
  int lane = tid & 63, wv = tid >> 6;
  int wm = wv & 1, wn = wv >> 1;
  int l16 = lane & 15, quad = lane >> 4;
  int lr = lane >> 2, lseg = lane & 3;
  if (MODE == 1) A += (size_t)blockIdx.x * M_PAD * K;  // head slice

  f32x4 acc[MFR][4];
#pragma unroll
  for (int i = 0; i < MFR; ++i)
#pragma unroll
    for (int j = 0; j < 4; ++j) acc[i][j] = (f32x4)(0.f);

  for (int k0 = 0; k0 < K; k0 += 32) {
#pragma unroll
    for (int c = wv; c < BM / 16; c += 4) {
      int gr = m0 + c * 16 + lr; gr = gr < M ? gr : M - 1;
      __builtin_amdgcn_global_load_lds(
          (const __attribute__((address_space(1))) void*)(A + (size_t)gr * K + k0 + lseg * 8),
          (__attribute__((address_space(3))) void*)(&Asl[c * 512]), 16, 0, 0);
    }
#pragma unroll
    for (int c = wv; c < 8; c += 4) {
      int gr = n0 + c * 16 + lr;
      __builtin_amdgcn_global_load_lds(
          (const __attribute__((address_space(1))) void*)(BT + (size_t)gr * K + k0 + lseg * 8),
          (__attribute__((address_space(3))) void*)(&Bsl[c * 512]), 16, 0, 0);
    }
    __syncthreads();
    bf16x8 af[MFR], bfr[4];
#pragma unroll
    for (int mf = 0; mf < MFR; ++mf)
      af[mf] = *(const bf16x8*)(&Asl[(wm * (BM / 2) + mf * 16 + l16) * 32 + quad * 8]);
#pragma unroll
    for (int nf = 0; nf < 4; ++nf)
      bfr[nf] = *(const bf16x8*)(&Bsl[(wn * 64 + nf * 16 + l16) * 32 + quad * 8]);
#pragma unroll
    for (int mf = 0; mf < MFR; ++mf)
#pragma unroll
      for (int nf = 0; nf < 4; ++nf)
        acc[mf][nf] = __builtin_amdgcn_mfma_f32_16x16x32_bf16(af[mf], bfr[nf], acc[mf][nf], 0, 0, 0);
    __syncthreads();
  }
  if (MODE == 0) {
#pragma unroll
    for (int mf = 0; mf < MFR; ++mf)
#pragma unroll
      for (int nf = 0; nf < 4; ++nf)
#pragma unroll
        for (int r = 0; r < 4; ++r) {
          int row = m0 + wm * (BM / 2) + mf * 16 + quad * 4 + r;
          int col = n0 + wn * 64 + nf * 16 + l16;
          C[(size_t)row * N + col] = f2b(acc[mf][nf][r]);
        }
  } else {
#pragma unroll
    for (int mf = 0; mf < MFR; ++mf)
#pragma unroll
      for (int r = 0; r < 4; ++r) {
        int row = m0 + wm * (BM / 2) + mf * 16 + quad * 4 + r;
        float sd = 0.f, dd = 0.f;
#pragma unroll
        for (int nf = 0; nf < 4; ++nf) {
          int col = n0 + wn * 64 + nf * 16 + l16;
          float cv = acc[mf][nf][r] + bias[col];
          cv = cv > 0.f ? cv : expm1f(cv);  // ELU
          C[(size_t)row * N + col] = f2b(cv);
          sd += cv * vs[col];
          dd += cv * vd[col];
        }
#pragma unroll
        for (int off = 1; off < 16; off <<= 1) {
          sd += __shfl_xor(sd, off);
          dd += __shfl_xor(dd, off);
        }
        if (l16 == 0 && row < M) {
          atomicAdd(&as2[row], sd);
          atomicAdd(&ad2[row], dd);
        }
      }
  }
}

// ---- layer-2 aggregate: one wave/node, 4 groups, packed acc ---------------
__global__ __launch_bounds__(256) void aggregate2_kernel(
    const unsigned short* __restrict__ t2b,
    const float* __restrict__ as2, const float* __restrict__ ad2,
    const int* __restrict__ offsets, const int* __restrict__ bsum,
    const int* __restrict__ csr_src,
    const float* __restrict__ bias, float* __restrict__ out, int n_nodes) {
  int node = blockIdx.x * 4 + (threadIdx.x >> 6);
  if (node >= n_nodes) return;
  int lane = threadIdx.x & 63;
  int g = lane >> 4, l16 = lane & 15;
  int lo = offsets[node] + bsum[node >> 10];
  int hi = offsets[node + 1] + bsum[(node + 1) >> 10];
  float ad = ad2[node];

  const uint4* t2v = (const uint4*)t2b;
  f32x2 acc[4];
#pragma unroll
  for (int k = 0; k < 4; ++k) acc[k] = (f32x2)(0.f);
  float denom = 0.f;
  int nit = (hi - lo + 3) >> 2;
  int j = lo + g;
  bool valid = j < hi;
  int s = valid ? csr_src[j] : node;
  float asv = as2[s];
  for (int i = 0; i < nit; ++i) {
    int jn = j + 4;
    bool vn = jn < hi;
    int sn = vn ? csr_src[jn] : node;
    float asv_n = as2[sn];
    uint4 tv = t2v[(size_t)s * 16 + l16];
    float w = valid ? __expf(lrelu(asv + ad)) : 0.f;
    accp(acc, w, tv);
    denom += w;
    j = jn; valid = vn; s = sn; asv = asv_n;
  }
  if (g == 0) {  // self loop
    uint4 tv = t2v[(size_t)node * 16 + l16];
    float w = __expf(lrelu(as2[node] + ad));
    accp(acc, w, tv);
    denom += w;
  }
#pragma unroll
  for (int k = 0; k < 4; ++k) {
    acc[k].x += __shfl_xor(acc[k].x, 16); acc[k].y += __shfl_xor(acc[k].y, 16);
    acc[k].x += __shfl_xor(acc[k].x, 32); acc[k].y += __shfl_xor(acc[k].y, 32);
  }
  denom += __shfl_xor(denom, 16);
  denom += __shfl_xor(denom, 32);
  if (g == 0) {
    float inv = 1.f / (denom + 1e-16f);
    float4 o0, o1;
    o0.x = acc[0].x * inv + bias[l16 * 8 + 0];
    o0.y = acc[0].y * inv + bias[l16 * 8 + 1];
    o0.z = acc[1].x * inv + bias[l16 * 8 + 2];
    o0.w = acc[1].y * inv + bias[l16 * 8 + 3];
    o1.x = acc[2].x * inv + bias[l16 * 8 + 4];
    o1.y = acc[2].y * inv + bias[l16 * 8 + 5];
    o1.z = acc[3].x * inv + bias[l16 * 8 + 6];
    o1.w = acc[3].y * inv + bias[l16 * 8 + 7];
    *(float4*)(out + (size_t)node * DOUT + l16 * 8) = o0;
    *(float4*)(out + (size_t)node * DOUT + l16 * 8 + 4) = o1;
  }
}

extern "C" void kernel_launch(void* const* d_in, const int* in_sizes, int n_in,
                              void* d_out, int out_size, void* d_ws, size_t ws_size,
                              hipStream_t stream) {
  const float* x     = (const float*)d_in[0];
  const int* ei      = (const int*)d_in[1];
  const int* etype   = (const int*)d_in[2];
  const float* rel   = (const float*)d_in[3];
  const float* W1    = (const float*)d_in[4];
  const float* at_s1 = (const float*)d_in[5];
  const float* at_d1 = (const float*)d_in[6];
  const float* b1    = (const float*)d_in[7];
  const float* W2    = (const float*)d_in[8];
  const float* at_s2 = (const float*)d_in[9];
  const float* at_d2 = (const float*)d_in[10];
  const float* b2v   = (const float*)d_in[11];
  float* out         = (float*)d_out;

  const int N = in_sizes[0] / D_IN;  // 20000
  const int E = in_sizes[2];         // 640000
  const int* srcv = ei;
  const int* dstv = ei + E;

  char* p = (char*)d_ws;
  auto carve = [&](size_t bytes) -> char* {
    char* r = p; p += (bytes + 255) & ~(size_t)255; return r;
  };
  // zeroed region (counters + as2/ad2 atomic accumulators)
  int*   counts  = (int*)carve((size_t)N * NREL * 4);
  int*   deg     = (int*)carve((size_t)N * 4);
  int*   offsets = (int*)carve(((size_t)N + 1) * 4);
  int*   cursor  = (int*)carve((size_t)N * 4);
  int*   bsum    = (int*)carve(64 * 4);
  float* as2     = (float*)carve((size_t)N * 4);
  float* ad2     = (float*)carve((size_t)N * 4);
  size_t zero_bytes = (size_t)(p - (char*)counts);
  // plain scratch
  float* as1     = (float*)carve((size_t)N * NHEADS * 4);
  float* ad1     = (float*)carve((size_t)N * NHEADS * 4);
  float* vs      = (float*)carve((size_t)HID1 * 4);
  float* vd      = (float*)carve((size_t)HID1 * 4);
  float* us4     = (float*)carve((size_t)D_IN * 4 * 4);
  float* ud4     = (float*)carve((size_t)D_IN * 4 * 4);
  int*   csr_src = (int*)carve((size_t)E * 4);
  unsigned short* W1T    = (unsigned short*)carve((size_t)HID1 * D_IN * 2);
  unsigned short* W2T    = (unsigned short*)carve((size_t)DOUT * HID1 * 2);
  unsigned short* x_modb = (unsigned short*)carve((size_t)N * D_IN * 2);
  unsigned short* agg_xb = (unsigned short*)carve((size_t)NHEADS * M_PAD * D_IN * 2);
  unsigned short* h2b    = (unsigned short*)carve((size_t)M_PAD * HID1 * 2);
  unsigned short* t2b    = (unsigned short*)carve((size_t)M_PAD * DOUT * 2);

  hipMemsetAsync(counts, 0, zero_bytes, stream);

  int eb = (E + 255) / 256;                          // 2500
  int cb = (D_IN * HID1 + HID1 * DOUT + 255) / 256;  // 768
  int nb = (N + 1023) / 1024;                        // 20
  prep_kernel<<<eb + cb + 2, 256, 0, stream>>>(srcv, dstv, etype, counts, deg, E, eb, cb,
                                               W1, W2, W1T, W2T, at_s1, at_d1, us4, ud4,
                                               at_s2, at_d2, vs, vd);
  scan_local<<<nb, 256, 0, stream>>>(deg, offsets, bsum, N);
  scan_blocks<<<1, 64, 0, stream>>>(bsum, nb, offsets, N);
  scatter_kernel<<<eb, 256, 0, stream>>>(srcv, dstv, offsets, bsum, cursor, csr_src, E);
  xmod_kernel<<<(N + 3) / 4, 256, 0, stream>>>(x, counts, rel, us4, ud4, x_modb, as1, ad1, N);
  aggregate1_kernel<<<(N + 3) / 4, 256, 0, stream>>>(x_modb, as1, ad1, offsets, bsum,
                                                     csr_src, agg_xb, N);
  mfma_gemm<128, 1><<<dim3(NHEADS, M_PAD / 128), 256, 0, stream>>>(
      agg_xb, W1T, h2b, N, HID1, D_IN, b1, vs, vd, as2, ad2);
  mfma_gemm<64, 0><<<dim3(DOUT / 128, M_PAD / 64), 256, 0, stream>>>(
      h2b, W2T, t2b, N, DOUT, HID1, nullptr, nullptr, nullptr, nullptr, nullptr);
  aggregate2_kernel<<<(N + 3) / 4, 256, 0, stream>>>(
      t2b, as2, ad2, offsets, bsum, csr_src, b2v, out, N);
}